// Round 7
// baseline (185.134 us; speedup 1.0000x reference)
//
#include <hip/hip_runtime.h>

#define EPSF 1e-8f
#define EPT 16  // edges per thread

typedef int iv4 __attribute__((ext_vector_type(4)));

__device__ __forceinline__ float frcp(float x) { return __builtin_amdgcn_rcpf(x); }
__device__ __forceinline__ float frsq(float x) { return __builtin_amdgcn_rsqf(x); }
__device__ __forceinline__ float sq(float x) { return x * x; }

// ln(1 + e^{-x}) for x >= 0, via HW v_exp_f32 (2^x) / v_log_f32 (log2 x)
__device__ __forceinline__ float sp_neg(float x) {
    return 0.69314718f * __builtin_amdgcn_logf(1.0f + __builtin_amdgcn_exp2f(-x * 1.44269504f));
}

// ---- full-math helpers (45-pair reg term keeps exact original math) ----
__device__ __forceinline__ float2 norm_pt(float x, float y) {
    if (x == 0.0f && y == 0.0f) { x = 1.0f; y = 1.0f; }
    float nrm = sqrtf(x * x + y * y);
    float inv = frcp(fmaxf(nrm, EPSF));
    return make_float2(x * inv, y * inv);
}

__device__ __forceinline__ float edge_cr_full(float x1, float y1, float x2, float y2) {
    float a = y1 - y2;
    float b = x2 - x1;
    float c = x1 * y2 - y1 * x2;
    float n2 = fmaxf(a * a + b * b, EPSF);
    float rn2 = frcp(n2);
    float x0 = -c * a * rn2;
    float y0 = -c * b * rn2;
    float t  = sqrtf(fmaxf(1.0f - c * c * rn2, 0.0f));
    float inv = frsq(n2);
    float px = -b * inv, py = a * inv;
    float2 q1 = norm_pt(x0 + t * px, y0 + t * py);
    float2 q2 = norm_pt(x0 - t * px, y0 - t * py);
    float d12 = sqrtf(sq(x1 - x2)   + sq(y1 - y2));
    float d34 = sqrtf(sq(q1.x - q2.x) + sq(q1.y - q2.y));
    float d13 = sqrtf(sq(x1 - q1.x) + sq(y1 - q1.y));
    float d24 = sqrtf(sq(x2 - q2.x) + sq(y2 - q2.y));
    float cr = d12 * d34 * frcp(d13 * d24 + EPSF);
    return fminf(fmaxf(cr, -5.0f), 5.0f);
}

__device__ __forceinline__ void block_reduce2(float v0, float v1, double* a0, double* a1) {
    #pragma unroll
    for (int o = 32; o > 0; o >>= 1) {
        v0 += __shfl_down(v0, o, 64);
        v1 += __shfl_down(v1, o, 64);
    }
    __shared__ float s0[8], s1[8];
    int lane = threadIdx.x & 63, wid = threadIdx.x >> 6;
    if (lane == 0) { s0[wid] = v0; s1[wid] = v1; }
    __syncthreads();
    if (threadIdx.x == 0) {
        float t0 = 0.0f, t1 = 0.0f;
        int nw = blockDim.x >> 6;
        for (int w = 0; w < nw; ++w) { t0 += s0[w]; t1 += s1[w]; }
        atomicAdd(a0, (double)t0);
        if (a1) atomicAdd(a1, (double)t1);
    }
}

// Encode each point as a 16-bit angle (2 MB table, fits every XCD L2 with headroom).
// atan2 is scale-invariant -> no normalize needed. Also zeroes acc + counter
// (replaces the memset launch; kernel ordering on stream guarantees visibility).
__global__ void norm_kernel(const float* __restrict__ z, unsigned short* __restrict__ tab,
                            int N, double* __restrict__ acc, unsigned* __restrict__ counter) {
    if (blockIdx.x == 0 && threadIdx.x == 0) {
        acc[0] = 0.0; acc[1] = 0.0; acc[2] = 0.0; acc[3] = 0.0;
        *counter = 0u;
    }
    int stride = gridDim.x * blockDim.x;
    for (int i = blockIdx.x * blockDim.x + threadIdx.x; i < N; i += stride) {
        float2 p = ((const float2*)z)[i];
        float x = p.x, y = p.y;
        if (x == 0.0f && y == 0.0f) { x = 1.0f; y = 1.0f; }
        float ang = atan2f(y, x);                       // [-pi, pi]
        int u = (int)lrintf(ang * 10430.378350470453f); // 65536/(2*pi)
        tab[i] = (unsigned short)(u & 0xFFFF);
    }
}

// Fused pos+neg edge kernel with last-block reg+finalize.
// cr identity chain: i1==p1, i2==p2 on unit circle => cr = min(d12^2 * 1e8, 5);
// d12^2 = 4 sin^2(dTheta/2), dTheta via exact mod-2^16 integer wrap.
template <bool USE_TAB>
__global__ __launch_bounds__(256)
void edge_kernel(const unsigned short* __restrict__ tab, const float* __restrict__ z,
                 const int* __restrict__ ei, int E,
                 const int* __restrict__ nei, int En,
                 const int* __restrict__ bsp, int N, int gp,
                 double* __restrict__ acc, unsigned* __restrict__ counter,
                 const int* __restrict__ ridx, int nreg,
                 float* __restrict__ out) {
    const bool is_pos = (int)blockIdx.x < gp;
    const int* idx;
    int cnt, blk0;
    if (is_pos) { idx = ei;  cnt = E;  blk0 = blockIdx.x; }
    else        { idx = nei; cnt = En; blk0 = blockIdx.x - gp; }
    const int* src = idx;
    const int* dst = idx + cnt;
    const int bs = bsp[0];
    const unsigned nm1 = (unsigned)(N - 1);

    float lsum = 0.0f, lcnt = 0.0f;
    long long base = ((long long)blk0 * blockDim.x + threadIdx.x) * EPT;

    if (base + EPT <= (long long)cnt) {
        iv4 s4[EPT / 4], d4[EPT / 4];
        #pragma unroll
        for (int k = 0; k < EPT / 4; ++k) {
            s4[k] = __builtin_nontemporal_load((const iv4*)(src + base) + k);
            d4[k] = __builtin_nontemporal_load((const iv4*)(dst + base) + k);
        }
        unsigned short ua[EPT], ub[EPT];
        float2 fa[EPT], fb[EPT];
        #pragma unroll
        for (int k = 0; k < EPT; ++k) {
            unsigned si = min((unsigned)s4[k >> 2][k & 3], nm1);
            unsigned di = min((unsigned)d4[k >> 2][k & 3], nm1);
            if (USE_TAB) {
                ua[k] = tab[si];
                ub[k] = tab[di];
            } else {
                fa[k] = ((const float2*)z)[si];
                fb[k] = ((const float2*)z)[di];
            }
        }
        #pragma unroll
        for (int k = 0; k < EPT; ++k) {
            float d2;
            if (USE_TAB) {
                int du = (short)(unsigned short)(ua[k] - ub[k]);       // exact mod-2^16 wrap
                float s = __sinf((float)du * 4.7936899621426287e-5f);  // pi/65536
                d2 = 4.0f * s * s;
            } else {
                float2 pa = norm_pt(fa[k].x, fa[k].y);
                float2 pb = norm_pt(fb[k].x, fb[k].y);
                float dx = pa.x - pb.x, dy = pa.y - pb.y;
                d2 = dx * dx + dy * dy;
            }
            float cr = fminf(d2 * 1e8f, 5.0f);
            float t = sp_neg(cr);            // softplus(-cr), cr >= 0
            if (is_pos) {
                int s = s4[k >> 2][k & 3], d = d4[k >> 2][k & 3];
                float m = (s < bs && d < bs) ? 1.0f : 0.0f;
                lsum += t * m;
                lcnt += m;
            } else {
                lsum += cr + t;              // softplus(cr) = cr + softplus(-cr)
            }
        }
    } else {
        for (long long i = base; i < (long long)cnt; ++i) {
            int s = src[i], d = dst[i];
            unsigned si = min((unsigned)s, nm1);
            unsigned di = min((unsigned)d, nm1);
            float d2;
            if (USE_TAB) {
                int du = (short)(unsigned short)(tab[si] - tab[di]);
                float ss = __sinf((float)du * 4.7936899621426287e-5f);
                d2 = 4.0f * ss * ss;
            } else {
                float2 a = ((const float2*)z)[si];
                float2 b = ((const float2*)z)[di];
                float2 pa = norm_pt(a.x, a.y);
                float2 pb = norm_pt(b.x, b.y);
                float dx = pa.x - pb.x, dy = pa.y - pb.y;
                d2 = dx * dx + dy * dy;
            }
            float cr = fminf(d2 * 1e8f, 5.0f);
            float t = sp_neg(cr);
            if (is_pos) {
                float m = (s < bs && d < bs) ? 1.0f : 0.0f;
                lsum += t * m; lcnt += m;
            } else {
                lsum += cr + t;
            }
        }
    }

    if (is_pos) block_reduce2(lsum, lcnt, &acc[0], &acc[1]);
    else        block_reduce2(lsum, 0.0f, &acc[2], nullptr);

    // ---- last-block-done: reg term + finalize (removes 2 kernel launches) ----
    __shared__ int s_last;
    if (threadIdx.x == 0) {
        __threadfence();                       // make this block's acc atomics visible
        unsigned prev = atomicAdd(counter, 1u);
        s_last = (prev == (unsigned)(gridDim.x - 1)) ? 1 : 0;
    }
    __syncthreads();
    if (s_last && threadIdx.x < 64) {
        __threadfence();                       // acquire side
        int npairs = nreg * (nreg - 1) / 2;
        float v = 0.0f;
        for (int p = threadIdx.x; p < npairs; p += 64) {
            int idx2 = p, i = 0, c2 = nreg - 1;
            while (idx2 >= c2) { idx2 -= c2; ++i; --c2; }
            int j = i + 1 + idx2;
            unsigned si = min((unsigned)ridx[i], nm1);
            unsigned di = min((unsigned)ridx[j], nm1);
            float2 zs = ((const float2*)z)[si];
            float2 zd = ((const float2*)z)[di];
            float2 p1 = norm_pt(zs.x, zs.y);
            float2 p2 = norm_pt(zd.x, zd.y);
            float cr = edge_cr_full(p1.x, p1.y, p2.x, p2.y);
            v += fabsf(cr * cr - 1.0f);        // cr1 == cr2 (identical num/den products)
        }
        #pragma unroll
        for (int o = 32; o > 0; o >>= 1) v += __shfl_down(v, o, 64);
        if (threadIdx.x == 0) {
            // coherent cross-XCD reads of the accumulators (RMW, device scope)
            double pos_s = atomicAdd(&acc[0], 0.0);
            double pos_c = atomicAdd(&acc[1], 0.0);
            double neg_s = atomicAdd(&acc[2], 0.0);
            double pos = pos_s / fmax(pos_c, 1.0);
            double neg = neg_s / (double)En;
            double reg = (double)v / (double)npairs;
            double tot = pos + neg + 0.1 * reg;
            tot = fmin(fmax(tot, 0.0), 5.0);
            out[0] = (float)tot;
        }
    }
}

extern "C" void kernel_launch(void* const* d_in, const int* in_sizes, int n_in,
                              void* d_out, int out_size, void* d_ws, size_t ws_size,
                              hipStream_t stream) {
    const float* z  = (const float*)d_in[0];
    const int* ei   = (const int*)d_in[1];
    const int* nei  = (const int*)d_in[2];
    const int* ridx = (const int*)d_in[3];
    const int* bsp  = (const int*)d_in[4];
    float* out = (float*)d_out;

    int N    = in_sizes[0] / 2;
    int E    = in_sizes[1] / 2;
    int Nn   = in_sizes[2] / 2;
    int nreg = in_sizes[3];

    // ws layout: [0,32): 4 doubles acc | [64,68): counter | [256, ...): u16 table
    double* acc = (double*)d_ws;
    unsigned* counter = (unsigned*)((char*)d_ws + 64);
    unsigned short* tab = (unsigned short*)((char*)d_ws + 256);
    size_t need = 256 + (size_t)N * sizeof(unsigned short);
    bool use_tab = (ws_size >= need);

    const int threads = 256;
    const long long per_blk = (long long)threads * EPT;   // 4096 edges per block
    int gp = (int)((E  + per_blk - 1) / per_blk);
    int gn = (int)((Nn + per_blk - 1) / per_blk);

    int gnorm = (N + threads * 4 - 1) / (threads * 4); if (gnorm > 1024) gnorm = 1024;
    if (gnorm < 1) gnorm = 1;
    norm_kernel<<<gnorm, threads, 0, stream>>>(z, tab, use_tab ? N : 0, acc, counter);

    if (use_tab) {
        edge_kernel<true><<<gp + gn, threads, 0, stream>>>(tab, z, ei, E, nei, Nn, bsp, N, gp,
                                                           acc, counter, ridx, nreg, out);
    } else {
        edge_kernel<false><<<gp + gn, threads, 0, stream>>>(nullptr, z, ei, E, nei, Nn, bsp, N, gp,
                                                            acc, counter, ridx, nreg, out);
    }
}

// Round 8
// 106.663 us; speedup vs baseline: 1.7357x; 1.7357x over previous
//
#include <hip/hip_runtime.h>

#define EPSF 1e-8f
#define EPT 16  // edges per thread

typedef int iv4 __attribute__((ext_vector_type(4)));

__device__ __forceinline__ float frcp(float x) { return __builtin_amdgcn_rcpf(x); }
__device__ __forceinline__ float frsq(float x) { return __builtin_amdgcn_rsqf(x); }
__device__ __forceinline__ float sq(float x) { return x * x; }

// ln(1 + e^{-x}) for x >= 0, via HW v_exp_f32 (2^x) / v_log_f32 (log2 x)
__device__ __forceinline__ float sp_neg(float x) {
    return 0.69314718f * __builtin_amdgcn_logf(1.0f + __builtin_amdgcn_exp2f(-x * 1.44269504f));
}

// ---- full-math helpers (45-pair reg term keeps exact original math) ----
__device__ __forceinline__ float2 norm_pt(float x, float y) {
    if (x == 0.0f && y == 0.0f) { x = 1.0f; y = 1.0f; }
    float nrm = sqrtf(x * x + y * y);
    float inv = frcp(fmaxf(nrm, EPSF));
    return make_float2(x * inv, y * inv);
}

__device__ __forceinline__ float edge_cr_full(float x1, float y1, float x2, float y2) {
    float a = y1 - y2;
    float b = x2 - x1;
    float c = x1 * y2 - y1 * x2;
    float n2 = fmaxf(a * a + b * b, EPSF);
    float rn2 = frcp(n2);
    float x0 = -c * a * rn2;
    float y0 = -c * b * rn2;
    float t  = sqrtf(fmaxf(1.0f - c * c * rn2, 0.0f));
    float inv = frsq(n2);
    float px = -b * inv, py = a * inv;
    float2 q1 = norm_pt(x0 + t * px, y0 + t * py);
    float2 q2 = norm_pt(x0 - t * px, y0 - t * py);
    float d12 = sqrtf(sq(x1 - x2)   + sq(y1 - y2));
    float d34 = sqrtf(sq(q1.x - q2.x) + sq(q1.y - q2.y));
    float d13 = sqrtf(sq(x1 - q1.x) + sq(y1 - q1.y));
    float d24 = sqrtf(sq(x2 - q2.x) + sq(y2 - q2.y));
    float cr = d12 * d34 * frcp(d13 * d24 + EPSF);
    return fminf(fmaxf(cr, -5.0f), 5.0f);
}

__device__ __forceinline__ void block_reduce2(float v0, float v1, double* a0, double* a1) {
    #pragma unroll
    for (int o = 32; o > 0; o >>= 1) {
        v0 += __shfl_down(v0, o, 64);
        v1 += __shfl_down(v1, o, 64);
    }
    __shared__ float s0[8], s1[8];
    int lane = threadIdx.x & 63, wid = threadIdx.x >> 6;
    if (lane == 0) { s0[wid] = v0; s1[wid] = v1; }
    __syncthreads();
    if (threadIdx.x == 0) {
        float t0 = 0.0f, t1 = 0.0f;
        int nw = blockDim.x >> 6;
        for (int w = 0; w < nw; ++w) { t0 += s0[w]; t1 += s1[w]; }
        atomicAdd(a0, (double)t0);
        if (a1) atomicAdd(a1, (double)t1);
    }
}

// Encode each point as a 16-bit angle (2 MB table, fits every XCD L2 with headroom).
// atan2 is scale-invariant -> no normalize needed. Also zeroes acc + counter
// (replaces the memset launch; kernel ordering on stream guarantees visibility).
__global__ void norm_kernel(const float* __restrict__ z, unsigned short* __restrict__ tab,
                            int N, double* __restrict__ acc, unsigned* __restrict__ counter) {
    if (blockIdx.x == 0 && threadIdx.x == 0) {
        acc[0] = 0.0; acc[1] = 0.0; acc[2] = 0.0; acc[3] = 0.0;
        *counter = 0u;
    }
    int stride = gridDim.x * blockDim.x;
    for (int i = blockIdx.x * blockDim.x + threadIdx.x; i < N; i += stride) {
        float2 p = ((const float2*)z)[i];
        float x = p.x, y = p.y;
        if (x == 0.0f && y == 0.0f) { x = 1.0f; y = 1.0f; }
        float ang = atan2f(y, x);                       // [-pi, pi]
        int u = (int)lrintf(ang * 10430.378350470453f); // 65536/(2*pi)
        tab[i] = (unsigned short)(u & 0xFFFF);
    }
}

// Fused pos+neg edge kernel with last-block reg+finalize.
// Ordering uses vmcnt-drained device-scope atomics ONLY — no __threadfence()!
// (gfx950 device fence = buffer_wbl2/buffer_inv sc1 = L2 invalidate; per-block
// it evicts the L2-resident table and doubled kernel time in R7.)
// cr identity chain: i1==p1, i2==p2 on unit circle => cr = min(d12^2 * 1e8, 5);
// d12^2 = 4 sin^2(dTheta/2), dTheta via exact mod-2^16 integer wrap.
template <bool USE_TAB>
__global__ __launch_bounds__(256)
void edge_kernel(const unsigned short* __restrict__ tab, const float* __restrict__ z,
                 const int* __restrict__ ei, int E,
                 const int* __restrict__ nei, int En,
                 const int* __restrict__ bsp, int N, int gp,
                 double* __restrict__ acc, unsigned* __restrict__ counter,
                 const int* __restrict__ ridx, int nreg,
                 float* __restrict__ out) {
    const bool is_pos = (int)blockIdx.x < gp;
    const int* idx;
    int cnt, blk0;
    if (is_pos) { idx = ei;  cnt = E;  blk0 = blockIdx.x; }
    else        { idx = nei; cnt = En; blk0 = blockIdx.x - gp; }
    const int* src = idx;
    const int* dst = idx + cnt;
    const int bs = bsp[0];
    const unsigned nm1 = (unsigned)(N - 1);

    float lsum = 0.0f, lcnt = 0.0f;
    long long base = ((long long)blk0 * blockDim.x + threadIdx.x) * EPT;

    if (base + EPT <= (long long)cnt) {
        iv4 s4[EPT / 4], d4[EPT / 4];
        #pragma unroll
        for (int k = 0; k < EPT / 4; ++k) {
            s4[k] = __builtin_nontemporal_load((const iv4*)(src + base) + k);
            d4[k] = __builtin_nontemporal_load((const iv4*)(dst + base) + k);
        }
        unsigned short ua[EPT], ub[EPT];
        float2 fa[EPT], fb[EPT];
        #pragma unroll
        for (int k = 0; k < EPT; ++k) {
            unsigned si = min((unsigned)s4[k >> 2][k & 3], nm1);
            unsigned di = min((unsigned)d4[k >> 2][k & 3], nm1);
            if (USE_TAB) {
                ua[k] = tab[si];
                ub[k] = tab[di];
            } else {
                fa[k] = ((const float2*)z)[si];
                fb[k] = ((const float2*)z)[di];
            }
        }
        #pragma unroll
        for (int k = 0; k < EPT; ++k) {
            float d2;
            if (USE_TAB) {
                int du = (short)(unsigned short)(ua[k] - ub[k]);       // exact mod-2^16 wrap
                float s = __sinf((float)du * 4.7936899621426287e-5f);  // pi/65536
                d2 = 4.0f * s * s;
            } else {
                float2 pa = norm_pt(fa[k].x, fa[k].y);
                float2 pb = norm_pt(fb[k].x, fb[k].y);
                float dx = pa.x - pb.x, dy = pa.y - pb.y;
                d2 = dx * dx + dy * dy;
            }
            float cr = fminf(d2 * 1e8f, 5.0f);
            float t = sp_neg(cr);            // softplus(-cr), cr >= 0
            if (is_pos) {
                int s = s4[k >> 2][k & 3], d = d4[k >> 2][k & 3];
                float m = (s < bs && d < bs) ? 1.0f : 0.0f;
                lsum += t * m;
                lcnt += m;
            } else {
                lsum += cr + t;              // softplus(cr) = cr + softplus(-cr)
            }
        }
    } else {
        for (long long i = base; i < (long long)cnt; ++i) {
            int s = src[i], d = dst[i];
            unsigned si = min((unsigned)s, nm1);
            unsigned di = min((unsigned)d, nm1);
            float d2;
            if (USE_TAB) {
                int du = (short)(unsigned short)(tab[si] - tab[di]);
                float ss = __sinf((float)du * 4.7936899621426287e-5f);
                d2 = 4.0f * ss * ss;
            } else {
                float2 a = ((const float2*)z)[si];
                float2 b = ((const float2*)z)[di];
                float2 pa = norm_pt(a.x, a.y);
                float2 pb = norm_pt(b.x, b.y);
                float dx = pa.x - pb.x, dy = pa.y - pb.y;
                d2 = dx * dx + dy * dy;
            }
            float cr = fminf(d2 * 1e8f, 5.0f);
            float t = sp_neg(cr);
            if (is_pos) {
                float m = (s < bs && d < bs) ? 1.0f : 0.0f;
                lsum += t * m; lcnt += m;
            } else {
                lsum += cr + t;
            }
        }
    }

    if (is_pos) block_reduce2(lsum, lcnt, &acc[0], &acc[1]);
    else        block_reduce2(lsum, 0.0f, &acc[2], nullptr);

    // ---- last-block-done, vmcnt-ordered (no cache fences) ----
    __shared__ int s_last;
    if (threadIdx.x == 0) {
        // Drain this thread's acc atomicAdds to the coherent point before the
        // counter RMW. vmcnt(0) ack == the add has been performed device-wide;
        // counter RMWs serialize at the same coherent point => transitive order.
        asm volatile("s_waitcnt vmcnt(0)" ::: "memory");
        unsigned prev = atomicAdd(counter, 1u);
        s_last = (prev == (unsigned)(gridDim.x - 1)) ? 1 : 0;
    }
    __syncthreads();
    if (s_last && threadIdx.x < 64) {
        int npairs = nreg * (nreg - 1) / 2;
        float v = 0.0f;
        for (int p = threadIdx.x; p < npairs; p += 64) {
            int idx2 = p, i = 0, c2 = nreg - 1;
            while (idx2 >= c2) { idx2 -= c2; ++i; --c2; }
            int j = i + 1 + idx2;
            unsigned si = min((unsigned)ridx[i], nm1);
            unsigned di = min((unsigned)ridx[j], nm1);
            float2 zs = ((const float2*)z)[si];
            float2 zd = ((const float2*)z)[di];
            float2 p1 = norm_pt(zs.x, zs.y);
            float2 p2 = norm_pt(zd.x, zd.y);
            float cr = edge_cr_full(p1.x, p1.y, p2.x, p2.y);
            v += fabsf(cr * cr - 1.0f);        // cr1 == cr2 (identical num/den products)
        }
        #pragma unroll
        for (int o = 32; o > 0; o >>= 1) v += __shfl_down(v, o, 64);
        if (threadIdx.x == 0) {
            // read accumulators via atomic RMW -> always served coherently
            double pos_s = atomicAdd(&acc[0], 0.0);
            double pos_c = atomicAdd(&acc[1], 0.0);
            double neg_s = atomicAdd(&acc[2], 0.0);
            double pos = pos_s / fmax(pos_c, 1.0);
            double neg = neg_s / (double)En;
            double reg = (double)v / (double)npairs;
            double tot = pos + neg + 0.1 * reg;
            tot = fmin(fmax(tot, 0.0), 5.0);
            out[0] = (float)tot;
        }
    }
}

extern "C" void kernel_launch(void* const* d_in, const int* in_sizes, int n_in,
                              void* d_out, int out_size, void* d_ws, size_t ws_size,
                              hipStream_t stream) {
    const float* z  = (const float*)d_in[0];
    const int* ei   = (const int*)d_in[1];
    const int* nei  = (const int*)d_in[2];
    const int* ridx = (const int*)d_in[3];
    const int* bsp  = (const int*)d_in[4];
    float* out = (float*)d_out;

    int N    = in_sizes[0] / 2;
    int E    = in_sizes[1] / 2;
    int Nn   = in_sizes[2] / 2;
    int nreg = in_sizes[3];

    // ws layout: [0,32): 4 doubles acc | [64,68): counter | [256, ...): u16 table
    double* acc = (double*)d_ws;
    unsigned* counter = (unsigned*)((char*)d_ws + 64);
    unsigned short* tab = (unsigned short*)((char*)d_ws + 256);
    size_t need = 256 + (size_t)N * sizeof(unsigned short);
    bool use_tab = (ws_size >= need);

    const int threads = 256;
    const long long per_blk = (long long)threads * EPT;   // 4096 edges per block
    int gp = (int)((E  + per_blk - 1) / per_blk);
    int gn = (int)((Nn + per_blk - 1) / per_blk);

    int gnorm = (N + threads * 4 - 1) / (threads * 4); if (gnorm > 1024) gnorm = 1024;
    if (gnorm < 1) gnorm = 1;
    norm_kernel<<<gnorm, threads, 0, stream>>>(z, tab, use_tab ? N : 0, acc, counter);

    if (use_tab) {
        edge_kernel<true><<<gp + gn, threads, 0, stream>>>(tab, z, ei, E, nei, Nn, bsp, N, gp,
                                                           acc, counter, ridx, nreg, out);
    } else {
        edge_kernel<false><<<gp + gn, threads, 0, stream>>>(nullptr, z, ei, E, nei, Nn, bsp, N, gp,
                                                            acc, counter, ridx, nreg, out);
    }
}

// Round 9
// 106.010 us; speedup vs baseline: 1.7464x; 1.0062x over previous
//
#include <hip/hip_runtime.h>

#define EPSF 1e-8f
#define EPT 16  // edges per thread

typedef int iv4 __attribute__((ext_vector_type(4)));

__device__ __forceinline__ float frcp(float x) { return __builtin_amdgcn_rcpf(x); }
__device__ __forceinline__ float frsq(float x) { return __builtin_amdgcn_rsqf(x); }
__device__ __forceinline__ float sq(float x) { return x * x; }

// ln(1 + e^{-x}) for x >= 0, via HW v_exp_f32 (2^x) / v_log_f32 (log2 x)
__device__ __forceinline__ float sp_neg(float x) {
    return 0.69314718f * __builtin_amdgcn_logf(1.0f + __builtin_amdgcn_exp2f(-x * 1.44269504f));
}

// ---- full-math helpers (45-pair reg term keeps exact original math) ----
__device__ __forceinline__ float2 norm_pt(float x, float y) {
    if (x == 0.0f && y == 0.0f) { x = 1.0f; y = 1.0f; }
    float nrm = sqrtf(x * x + y * y);
    float inv = frcp(fmaxf(nrm, EPSF));
    return make_float2(x * inv, y * inv);
}

__device__ __forceinline__ float edge_cr_full(float x1, float y1, float x2, float y2) {
    float a = y1 - y2;
    float b = x2 - x1;
    float c = x1 * y2 - y1 * x2;
    float n2 = fmaxf(a * a + b * b, EPSF);
    float rn2 = frcp(n2);
    float x0 = -c * a * rn2;
    float y0 = -c * b * rn2;
    float t  = sqrtf(fmaxf(1.0f - c * c * rn2, 0.0f));
    float inv = frsq(n2);
    float px = -b * inv, py = a * inv;
    float2 q1 = norm_pt(x0 + t * px, y0 + t * py);
    float2 q2 = norm_pt(x0 - t * px, y0 - t * py);
    float d12 = sqrtf(sq(x1 - x2)   + sq(y1 - y2));
    float d34 = sqrtf(sq(q1.x - q2.x) + sq(q1.y - q2.y));
    float d13 = sqrtf(sq(x1 - q1.x) + sq(y1 - q1.y));
    float d24 = sqrtf(sq(x2 - q2.x) + sq(y2 - q2.y));
    float cr = d12 * d34 * frcp(d13 * d24 + EPSF);
    return fminf(fmaxf(cr, -5.0f), 5.0f);
}

__device__ __forceinline__ void block_reduce2(float v0, float v1, double* a0, double* a1) {
    #pragma unroll
    for (int o = 32; o > 0; o >>= 1) {
        v0 += __shfl_down(v0, o, 64);
        v1 += __shfl_down(v1, o, 64);
    }
    __shared__ float s0[8], s1[8];
    int lane = threadIdx.x & 63, wid = threadIdx.x >> 6;
    if (lane == 0) { s0[wid] = v0; s1[wid] = v1; }
    __syncthreads();
    if (threadIdx.x == 0) {
        float t0 = 0.0f, t1 = 0.0f;
        int nw = blockDim.x >> 6;
        for (int w = 0; w < nw; ++w) { t0 += s0[w]; t1 += s1[w]; }
        atomicAdd(a0, (double)t0);
        if (a1) atomicAdd(a1, (double)t1);
    }
}

// Encode each point as a 16-bit angle (2 MB table, fits every XCD L2 with headroom).
// atan2 is scale-invariant -> no normalize needed. Also zeroes acc + counter
// (replaces the memset launch; kernel ordering on stream guarantees visibility).
__global__ void norm_kernel(const float* __restrict__ z, unsigned short* __restrict__ tab,
                            int N, double* __restrict__ acc, unsigned* __restrict__ counter) {
    if (blockIdx.x == 0 && threadIdx.x == 0) {
        acc[0] = 0.0; acc[1] = 0.0; acc[2] = 0.0; acc[3] = 0.0;
        *counter = 0u;
    }
    int stride = gridDim.x * blockDim.x;
    for (int i = blockIdx.x * blockDim.x + threadIdx.x; i < N; i += stride) {
        float2 p = ((const float2*)z)[i];
        float x = p.x, y = p.y;
        if (x == 0.0f && y == 0.0f) { x = 1.0f; y = 1.0f; }
        float ang = atan2f(y, x);                       // [-pi, pi]
        int u = (int)lrintf(ang * 10430.378350470453f); // 65536/(2*pi)
        tab[i] = (unsigned short)(u & 0xFFFF);
    }
}

// Fused pos+neg edge kernel with last-block reg+finalize.
// Ordering uses vmcnt-drained device-scope atomics ONLY — no __threadfence()!
// (gfx950 device fence = buffer_wbl2/buffer_inv sc1 = L2 invalidate; per-block
// it evicts the L2-resident table and doubled kernel time in R7.)
// cr identity chain: i1==p1, i2==p2 on unit circle => cr = min(d12^2 * 1e8, 5);
// d12^2 = 4 sin^2(dTheta/2), dTheta via exact mod-2^16 integer wrap.
template <bool USE_TAB>
__global__ __launch_bounds__(256)
void edge_kernel(const unsigned short* __restrict__ tab, const float* __restrict__ z,
                 const int* __restrict__ ei, int E,
                 const int* __restrict__ nei, int En,
                 const int* __restrict__ bsp, int N, int gp,
                 double* __restrict__ acc, unsigned* __restrict__ counter,
                 const int* __restrict__ ridx, int nreg,
                 float* __restrict__ out) {
    const bool is_pos = (int)blockIdx.x < gp;
    const int* idx;
    int cnt, blk0;
    if (is_pos) { idx = ei;  cnt = E;  blk0 = blockIdx.x; }
    else        { idx = nei; cnt = En; blk0 = blockIdx.x - gp; }
    const int* src = idx;
    const int* dst = idx + cnt;
    const int bs = bsp[0];
    const unsigned nm1 = (unsigned)(N - 1);

    float lsum = 0.0f, lcnt = 0.0f;
    long long base = ((long long)blk0 * blockDim.x + threadIdx.x) * EPT;

    if (base + EPT <= (long long)cnt) {
        iv4 s4[EPT / 4], d4[EPT / 4];
        #pragma unroll
        for (int k = 0; k < EPT / 4; ++k) {
            s4[k] = __builtin_nontemporal_load((const iv4*)(src + base) + k);
            d4[k] = __builtin_nontemporal_load((const iv4*)(dst + base) + k);
        }
        unsigned short ua[EPT], ub[EPT];
        float2 fa[EPT], fb[EPT];
        #pragma unroll
        for (int k = 0; k < EPT; ++k) {
            unsigned si = min((unsigned)s4[k >> 2][k & 3], nm1);
            unsigned di = min((unsigned)d4[k >> 2][k & 3], nm1);
            if (USE_TAB) {
                ua[k] = tab[si];
                ub[k] = tab[di];
            } else {
                fa[k] = ((const float2*)z)[si];
                fb[k] = ((const float2*)z)[di];
            }
        }
        #pragma unroll
        for (int k = 0; k < EPT; ++k) {
            float d2;
            if (USE_TAB) {
                int du = (short)(unsigned short)(ua[k] - ub[k]);       // exact mod-2^16 wrap
                float s = __sinf((float)du * 4.7936899621426287e-5f);  // pi/65536
                d2 = 4.0f * s * s;
            } else {
                float2 pa = norm_pt(fa[k].x, fa[k].y);
                float2 pb = norm_pt(fb[k].x, fb[k].y);
                float dx = pa.x - pb.x, dy = pa.y - pb.y;
                d2 = dx * dx + dy * dy;
            }
            float cr = fminf(d2 * 1e8f, 5.0f);
            float t = sp_neg(cr);            // softplus(-cr), cr >= 0
            if (is_pos) {
                int s = s4[k >> 2][k & 3], d = d4[k >> 2][k & 3];
                float m = (s < bs && d < bs) ? 1.0f : 0.0f;
                lsum += t * m;
                lcnt += m;
            } else {
                lsum += cr + t;              // softplus(cr) = cr + softplus(-cr)
            }
        }
    } else {
        for (long long i = base; i < (long long)cnt; ++i) {
            int s = src[i], d = dst[i];
            unsigned si = min((unsigned)s, nm1);
            unsigned di = min((unsigned)d, nm1);
            float d2;
            if (USE_TAB) {
                int du = (short)(unsigned short)(tab[si] - tab[di]);
                float ss = __sinf((float)du * 4.7936899621426287e-5f);
                d2 = 4.0f * ss * ss;
            } else {
                float2 a = ((const float2*)z)[si];
                float2 b = ((const float2*)z)[di];
                float2 pa = norm_pt(a.x, a.y);
                float2 pb = norm_pt(b.x, b.y);
                float dx = pa.x - pb.x, dy = pa.y - pb.y;
                d2 = dx * dx + dy * dy;
            }
            float cr = fminf(d2 * 1e8f, 5.0f);
            float t = sp_neg(cr);
            if (is_pos) {
                float m = (s < bs && d < bs) ? 1.0f : 0.0f;
                lsum += t * m; lcnt += m;
            } else {
                lsum += cr + t;
            }
        }
    }

    if (is_pos) block_reduce2(lsum, lcnt, &acc[0], &acc[1]);
    else        block_reduce2(lsum, 0.0f, &acc[2], nullptr);

    // ---- last-block-done, vmcnt-ordered (no cache fences) ----
    __shared__ int s_last;
    if (threadIdx.x == 0) {
        // Drain this wave's acc atomicAdds to the coherent point before the
        // counter RMW; counter RMWs serialize there => transitive order.
        asm volatile("s_waitcnt vmcnt(0)" ::: "memory");
        unsigned prev = atomicAdd(counter, 1u);
        s_last = (prev == (unsigned)(gridDim.x - 1)) ? 1 : 0;
    }
    __syncthreads();
    if (s_last && threadIdx.x < 64) {
        int npairs = nreg * (nreg - 1) / 2;
        float v = 0.0f;
        for (int p = threadIdx.x; p < npairs; p += 64) {
            int idx2 = p, i = 0, c2 = nreg - 1;
            while (idx2 >= c2) { idx2 -= c2; ++i; --c2; }
            int j = i + 1 + idx2;
            unsigned si = min((unsigned)ridx[i], nm1);
            unsigned di = min((unsigned)ridx[j], nm1);
            float2 zs = ((const float2*)z)[si];
            float2 zd = ((const float2*)z)[di];
            float2 p1 = norm_pt(zs.x, zs.y);
            float2 p2 = norm_pt(zd.x, zd.y);
            float cr = edge_cr_full(p1.x, p1.y, p2.x, p2.y);
            v += fabsf(cr * cr - 1.0f);        // cr1 == cr2 (identical num/den products)
        }
        #pragma unroll
        for (int o = 32; o > 0; o >>= 1) v += __shfl_down(v, o, 64);
        if (threadIdx.x == 0) {
            // read accumulators via atomic RMW -> always served coherently
            double pos_s = atomicAdd(&acc[0], 0.0);
            double pos_c = atomicAdd(&acc[1], 0.0);
            double neg_s = atomicAdd(&acc[2], 0.0);
            double pos = pos_s / fmax(pos_c, 1.0);
            double neg = neg_s / (double)En;
            double reg = (double)v / (double)npairs;
            double tot = pos + neg + 0.1 * reg;
            tot = fmin(fmax(tot, 0.0), 5.0);
            out[0] = (float)tot;
        }
    }
}

extern "C" void kernel_launch(void* const* d_in, const int* in_sizes, int n_in,
                              void* d_out, int out_size, void* d_ws, size_t ws_size,
                              hipStream_t stream) {
    const float* z  = (const float*)d_in[0];
    const int* ei   = (const int*)d_in[1];
    const int* nei  = (const int*)d_in[2];
    const int* ridx = (const int*)d_in[3];
    const int* bsp  = (const int*)d_in[4];
    float* out = (float*)d_out;

    int N    = in_sizes[0] / 2;
    int E    = in_sizes[1] / 2;
    int Nn   = in_sizes[2] / 2;
    int nreg = in_sizes[3];

    // ws layout: [0,32): 4 doubles acc | [4096,4100): counter (own page ->
    // different L2 slice than the acc hot line) | [8192, ...): u16 table
    double* acc = (double*)d_ws;
    unsigned* counter = (unsigned*)((char*)d_ws + 4096);
    unsigned short* tab = (unsigned short*)((char*)d_ws + 8192);
    size_t need = 8192 + (size_t)N * sizeof(unsigned short);
    bool use_tab = (ws_size >= need);

    const int threads = 256;
    const long long per_blk = (long long)threads * EPT;   // 4096 edges per block
    int gp = (int)((E  + per_blk - 1) / per_blk);
    int gn = (int)((Nn + per_blk - 1) / per_blk);

    int gnorm = (N + threads * 4 - 1) / (threads * 4); if (gnorm > 1024) gnorm = 1024;
    if (gnorm < 1) gnorm = 1;
    norm_kernel<<<gnorm, threads, 0, stream>>>(z, tab, use_tab ? N : 0, acc, counter);

    if (use_tab) {
        edge_kernel<true><<<gp + gn, threads, 0, stream>>>(tab, z, ei, E, nei, Nn, bsp, N, gp,
                                                           acc, counter, ridx, nreg, out);
    } else {
        edge_kernel<false><<<gp + gn, threads, 0, stream>>>(nullptr, z, ei, E, nei, Nn, bsp, N, gp,
                                                            acc, counter, ridx, nreg, out);
    }
}